// Round 5
// baseline (157.504 us; speedup 1.0000x reference)
//
#include <hip/hip_runtime.h>
#include <stdint.h>

#define BATCH 8
#define SEQ   2048
#define DIM   256
#define NKV   64                 // kv tiles of 32 rows
#define KT    16384              // fragment bytes per 32-row tile (16 frags x 1KB)
#define NWT   16                 // 512/32 W k-tiles
#define VOFF  ((size_t)BATCH * NKV * KT)          // 8 MiB
#define WOFF  (VOFF + (size_t)BATCH * NKV * KT)   // 16 MiB
#define C1    0.090215498f       // (1/16) * log2(e), folded into K at prep

typedef __attribute__((ext_vector_type(8))) short bf16x8;
typedef __attribute__((ext_vector_type(4))) float f32x4;
typedef __attribute__((ext_vector_type(4))) unsigned int u32x4;

__device__ __forceinline__ unsigned short f2bf(float x) {
    unsigned u = __float_as_uint(x);
    unsigned r = u + 0x7fffu + ((u >> 16) & 1u);     // RNE
    return (unsigned short)(r >> 16);
}
__device__ __forceinline__ unsigned pack2(float a, float b) {
    return (unsigned)f2bf(a) | ((unsigned)f2bf(b) << 16);
}
__device__ __forceinline__ float exp2_fast(float x) {   // raw v_exp_f32; args bounded above, hw flushes big negatives to 0
    float r;
    asm("v_exp_f32 %0, %1" : "=v"(r) : "v"(x));
    return r;
}
__device__ __forceinline__ unsigned cvt_pk_bf16(float lo, float hi) {
    unsigned r;
    asm("v_cvt_pk_bf16_f32 %0, %1, %2" : "=v"(r) : "v"(lo), "v"(hi));
    return r;
}

// Build fragment-major bf16 images: each MFMA operand tile = 1KB block, lane-ordered,
// so the main loop's operand fetch is one coalesced 16B/lane global load (L2-resident).
// K is pre-scaled by C1 = scale*log2e so the softmax needs no multiplies.
__global__ void prep_frags(const float* __restrict__ K, const float* __restrict__ V,
                           const float* __restrict__ W, uint8_t* __restrict__ ws) {
    const int bid = blockIdx.x, tid = threadIdx.x;
    const int lane = tid & 63, fb = tid >> 6, g = lane >> 4, nn = lane & 15;
    if (bid < BATCH * NKV) {
        const float* src = K + (size_t)bid * 32 * DIM;
        uint8_t* dst = ws + (size_t)bid * KT;
#pragma unroll
        for (int p = 0; p < 4; ++p) {
            int f = p * 4 + fb;
            int row = (f >> 3) * 16 + nn, col = (f & 7) * 32 + g * 8;
            float4 a = *(const float4*)(src + (size_t)row * DIM + col);
            float4 c = *(const float4*)(src + (size_t)row * DIM + col + 4);
            u32x4 u = {pack2(a.x * C1, a.y * C1), pack2(a.z * C1, a.w * C1),
                       pack2(c.x * C1, c.y * C1), pack2(c.z * C1, c.w * C1)};
            *(u32x4*)(dst + f * 1024 + lane * 16) = u;
        }
    } else {
        const float* srcb;
        uint8_t* dst;
        if (bid < 2 * BATCH * NKV) {
            int id = bid - BATCH * NKV;
            srcb = V + (size_t)id * 32 * DIM;
            dst = ws + VOFF + (size_t)id * KT;
        } else {
            int wt = bid - 2 * BATCH * NKV;
            srcb = W + (size_t)wt * 32 * DIM;
            dst = ws + WOFF + (size_t)wt * KT;
        }
#pragma unroll
        for (int p = 0; p < 4; ++p) {
            int d = p * 4 + fb;
            float v[8];
#pragma unroll
            for (int j = 0; j < 8; ++j)
                v[j] = srcb[(size_t)(g * 8 + j) * DIM + d * 16 + nn];
            u32x4 u = {pack2(v[0], v[1]), pack2(v[2], v[3]),
                       pack2(v[4], v[5]), pack2(v[6], v[7])};
            *(u32x4*)(dst + d * 1024 + lane * 16) = u;
        }
    }
}

// smem: pbuf 4x1280 [0,5120) | cbuf f32[16][256] [5120,21504) |
//       cbn bf16[16][264] [21504,29952) | mws[4][16] | lws[4][16] | lgb[16]
#define SMEM_BYTES 30528

__launch_bounds__(256, 3)
__global__ void attn_main(const float* __restrict__ Q, const float* __restrict__ bias,
                          const uint8_t* __restrict__ ws, float* __restrict__ out) {
    __shared__ __align__(16) uint8_t smem[SMEM_BYTES];
    float* cbuf = (float*)(smem + 5120);
    uint8_t* cbn = smem + 21504;
    float* mws = (float*)(smem + 29952);
    float* lws = (float*)(smem + 30208);
    float* lgb = (float*)(smem + 30464);

    const int tid = threadIdx.x;
    const int wid = tid >> 6, lane = tid & 63, g = lane >> 4, nn = lane & 15;
    uint8_t* pbuf = smem + wid * 1280;
    const int b = blockIdx.x & 7, qg = blockIdx.x >> 3;   // batch -> XCD affinity
    const int q0 = qg * 16;

    // zero the merge accumulator (visibility ordered by the first __syncthreads below)
    {
        f32x4 z = {0.f, 0.f, 0.f, 0.f};
        float* p = cbuf + tid * 16;
#pragma unroll
        for (int i = 0; i < 4; ++i) *(f32x4*)(p + i * 4) = z;
    }

    // Q fragments (A-layout: row = nn, k = t8*32 + g*8 + j); identical in all 4 waves
    bf16x8 qf[8];
    {
        const float* qrow = Q + ((size_t)b * SEQ + q0 + nn) * DIM + g * 8;
#pragma unroll
        for (int t8 = 0; t8 < 8; ++t8) {
            float4 a = *(const float4*)(qrow + t8 * 32);
            float4 c = *(const float4*)(qrow + t8 * 32 + 4);
            union { bf16x8 v; unsigned u[4]; } tmp;
            tmp.u[0] = pack2(a.x, a.y); tmp.u[1] = pack2(a.z, a.w);
            tmp.u[2] = pack2(c.x, c.y); tmp.u[3] = pack2(c.z, c.w);
            qf[t8] = tmp.v;
        }
    }

    f32x4 ctx[16];
#pragma unroll
    for (int d = 0; d < 16; ++d) ctx[d] = (f32x4){0.f, 0.f, 0.f, 0.f};
    float m[4] = {-1e30f, -1e30f, -1e30f, -1e30f};   // in log2 units (K pre-scaled by C1)
    float l[4] = {0.f, 0.f, 0.f, 0.f};               // per-lane partials; reduced after loop

    // each wave owns a contiguous KV quarter; no barriers in this loop
    const uint8_t* kws = ws + ((size_t)b * NKV + wid * 16) * KT + lane * 16;
    const uint8_t* vws = ws + VOFF + ((size_t)b * NKV + wid * 16) * KT + lane * 16;

    for (int t = 0; t < 16; ++t) {
        const uint8_t* kf = kws + (size_t)t * KT;
        const uint8_t* vf = vws + (size_t)t * KT;
        // ---- S = Q K^T (already in log2 units) ----
        f32x4 s[2];
#pragma unroll
        for (int t2 = 0; t2 < 2; ++t2) {
            bf16x8 kb[8];
#pragma unroll
            for (int kk = 0; kk < 8; ++kk)
                kb[kk] = *(const bf16x8*)(kf + (t2 * 8 + kk) * 1024);
            f32x4 acc = (f32x4){0.f, 0.f, 0.f, 0.f};
#pragma unroll
            for (int kk = 0; kk < 8; ++kk)
                acc = __builtin_amdgcn_mfma_f32_16x16x32_bf16(qf[kk], kb[kk], acc, 0, 0, 0);
            s[t2] = acc;
        }
        // ---- defer-max online softmax: rescale only when a row max grows past THR=8 ----
        int need = 0;
        float smax[4];
#pragma unroll
        for (int r = 0; r < 4; ++r) {
            smax[r] = fmaxf(s[0][r], s[1][r]);
            need |= (smax[r] > m[r] + 8.0f);
        }
        if (__any(need)) {                          // wave-uniform; taken ~only at t=0
#pragma unroll
            for (int r = 0; r < 4; ++r) {
                float v = smax[r];
                v = fmaxf(v, __shfl_xor(v, 1));
                v = fmaxf(v, __shfl_xor(v, 2));
                v = fmaxf(v, __shfl_xor(v, 4));
                v = fmaxf(v, __shfl_xor(v, 8));
                float mn = fmaxf(m[r], v);
                float sc = exp2_fast(m[r] - mn);
                m[r] = mn;
                l[r] *= sc;
#pragma unroll
                for (int d = 0; d < 16; ++d) ctx[d][r] *= sc;
            }
        }
#pragma unroll
        for (int r = 0; r < 4; ++r) {
            float p0 = exp2_fast(s[0][r] - m[r]);   // bounded by 2^8
            float p1 = exp2_fast(s[1][r] - m[r]);
            l[r] += p0 + p1;
            unsigned pk = cvt_pk_bf16(p0, p1);
            *(unsigned short*)(pbuf + (g * 4 + r) * 80 + nn * 2)      = (unsigned short)pk;
            *(unsigned short*)(pbuf + (g * 4 + r) * 80 + 32 + nn * 2) = (unsigned short)(pk >> 16);
        }
        // ---- ctx += P V (P transposed via per-wave LDS; wave-internal, no barrier) ----
        bf16x8 pa = *(const bf16x8*)(pbuf + nn * 80 + g * 16);
#pragma unroll
        for (int d = 0; d < 16; ++d) {
            bf16x8 vv = *(const bf16x8*)(vf + d * 1024);
            ctx[d] = __builtin_amdgcn_mfma_f32_16x16x32_bf16(pa, vv, ctx[d], 0, 0, 0);
        }
    }

    // reduce per-lane l partials across the 16 kv lanes (once, not per tile)
#pragma unroll
    for (int r = 0; r < 4; ++r) {
        float v = l[r];
        v += __shfl_xor(v, 1);
        v += __shfl_xor(v, 2);
        v += __shfl_xor(v, 4);
        v += __shfl_xor(v, 8);
        l[r] = v;
    }

    // ---- merge the 4 KV-split partials (m, l, ctx) ----
    if (nn == 0) {
#pragma unroll
        for (int r = 0; r < 4; ++r) {
            mws[wid * 16 + g * 4 + r] = m[r];
            lws[wid * 16 + g * 4 + r] = l[r];
        }
    }
    __syncthreads();
    float sc[4];
#pragma unroll
    for (int r = 0; r < 4; ++r) {
        int row = g * 4 + r;
        float m0 = mws[row], m1 = mws[16 + row], m2 = mws[32 + row], m3 = mws[48 + row];
        float mg = fmaxf(fmaxf(m0, m1), fmaxf(m2, m3));
        float lg = lws[row]      * exp2_fast(m0 - mg)
                 + lws[16 + row] * exp2_fast(m1 - mg)
                 + lws[32 + row] * exp2_fast(m2 - mg)
                 + lws[48 + row] * exp2_fast(m3 - mg);
        sc[r] = exp2_fast(m[r] - mg);
        if (wid == 0 && nn == 0) lgb[row] = lg;
    }
    // sequential accumulate into cbuf (deterministic)
    for (int w = 0; w < 4; ++w) {
        if (wid == w) {
#pragma unroll
            for (int d = 0; d < 16; ++d) {
#pragma unroll
                for (int r = 0; r < 4; ++r) {
                    float* p = cbuf + (g * 4 + r) * 256 + d * 16 + nn;
                    *p += ctx[d][r] * sc[r];
                }
            }
        }
        __syncthreads();
    }
    // normalize + convert to bf16 image cbn[16][264]
    {
        int row = tid >> 4, c0 = (tid & 15) * 16;
        float il = 1.0f / lgb[row];
        const float* src = cbuf + row * 256 + c0;
        uint8_t* dp = cbn + row * 528 + c0 * 2;
#pragma unroll
        for (int i = 0; i < 2; ++i) {
            f32x4 a = *(const f32x4*)(src + i * 8);
            f32x4 c = *(const f32x4*)(src + i * 8 + 4);
            u32x4 u = {pack2(a[0] * il, a[1] * il), pack2(a[2] * il, a[3] * il),
                       pack2(c[0] * il, c[1] * il), pack2(c[2] * il, c[3] * il)};
            *(u32x4*)(dp + i * 16) = u;
        }
    }
    __syncthreads();

    // ---- epilogue: out = [ctxn, Q] @ W + b; wave wid owns output cols [wid*64, wid*64+64) ----
    f32x4 oacc[4];
#pragma unroll
    for (int dd = 0; dd < 4; ++dd) oacc[dd] = (f32x4){0.f, 0.f, 0.f, 0.f};
    const uint8_t* wws = ws + WOFF + lane * 16;
    for (int wt = 0; wt < NWT; ++wt) {
        bf16x8 af;
        if (wt < 8) af = *(const bf16x8*)(cbn + nn * 528 + wt * 64 + g * 16);
        else        af = qf[wt - 8];
#pragma unroll
        for (int dd = 0; dd < 4; ++dd) {
            bf16x8 wf = *(const bf16x8*)(wws + (size_t)(wt * 16 + wid * 4 + dd) * 1024);
            oacc[dd] = __builtin_amdgcn_mfma_f32_16x16x32_bf16(af, wf, oacc[dd], 0, 0, 0);
        }
    }
    float* obase = out + ((size_t)b * SEQ + q0) * DIM + wid * 64;
#pragma unroll
    for (int dd = 0; dd < 4; ++dd) {
        float bv = bias[wid * 64 + dd * 16 + nn];
#pragma unroll
        for (int r = 0; r < 4; ++r)
            obase[(size_t)(g * 4 + r) * DIM + dd * 16 + nn] = oacc[dd][r] + bv;
    }
}

extern "C" void kernel_launch(void* const* d_in, const int* in_sizes, int n_in,
                              void* d_out, int out_size, void* d_ws, size_t ws_size,
                              hipStream_t stream) {
    const float* Q    = (const float*)d_in[0];
    const float* K    = (const float*)d_in[1];
    const float* V    = (const float*)d_in[2];
    const float* W    = (const float*)d_in[3];
    const float* bias = (const float*)d_in[4];
    float* out = (float*)d_out;
    uint8_t* ws = (uint8_t*)d_ws;
    prep_frags<<<2 * BATCH * NKV + NWT, 256, 0, stream>>>(K, V, W, ws);
    attn_main<<<BATCH * SEQ / 16, 256, 0, stream>>>(Q, bias, ws, out);
}

// Round 6
// 136.861 us; speedup vs baseline: 1.1508x; 1.1508x over previous
//
#include <hip/hip_runtime.h>
#include <stdint.h>

#define BATCH 8
#define SEQ   2048
#define DIM   256
#define NKV   64                 // kv tiles of 32 rows
#define KT    16384              // fragment bytes per 32-row tile (16 frags x 1KB)
#define NWT   16                 // 512/32 W k-tiles
#define VOFF  ((size_t)BATCH * NKV * KT)          // 8 MiB
#define WOFF  (VOFF + (size_t)BATCH * NKV * KT)   // 16 MiB
#define C1    0.090215498f       // (1/16) * log2(e), folded into K at prep

typedef __attribute__((ext_vector_type(8))) short bf16x8;
typedef __attribute__((ext_vector_type(4))) float f32x4;
typedef __attribute__((ext_vector_type(4))) unsigned int u32x4;

__device__ __forceinline__ unsigned short f2bf(float x) {
    unsigned u = __float_as_uint(x);
    unsigned r = u + 0x7fffu + ((u >> 16) & 1u);     // RNE
    return (unsigned short)(r >> 16);
}
__device__ __forceinline__ unsigned pack2(float a, float b) {
    return (unsigned)f2bf(a) | ((unsigned)f2bf(b) << 16);
}
__device__ __forceinline__ float exp2_fast(float x) {   // raw v_exp_f32; args bounded above
    float r;
    asm("v_exp_f32 %0, %1" : "=v"(r) : "v"(x));
    return r;
}
__device__ __forceinline__ unsigned cvt_pk_bf16(float lo, float hi) {
    unsigned r;
    asm("v_cvt_pk_bf16_f32 %0, %1, %2" : "=v"(r) : "v"(lo), "v"(hi));
    return r;
}

// Fragment-major bf16 images; K pre-scaled by C1 so softmax needs no multiplies.
__global__ void prep_frags(const float* __restrict__ K, const float* __restrict__ V,
                           const float* __restrict__ W, uint8_t* __restrict__ ws) {
    const int bid = blockIdx.x, tid = threadIdx.x;
    const int lane = tid & 63, fb = tid >> 6, g = lane >> 4, nn = lane & 15;
    if (bid < BATCH * NKV) {
        const float* src = K + (size_t)bid * 32 * DIM;
        uint8_t* dst = ws + (size_t)bid * KT;
#pragma unroll
        for (int p = 0; p < 4; ++p) {
            int f = p * 4 + fb;
            int row = (f >> 3) * 16 + nn, col = (f & 7) * 32 + g * 8;
            float4 a = *(const float4*)(src + (size_t)row * DIM + col);
            float4 c = *(const float4*)(src + (size_t)row * DIM + col + 4);
            u32x4 u = {pack2(a.x * C1, a.y * C1), pack2(a.z * C1, a.w * C1),
                       pack2(c.x * C1, c.y * C1), pack2(c.z * C1, c.w * C1)};
            *(u32x4*)(dst + f * 1024 + lane * 16) = u;
        }
    } else {
        const float* srcb;
        uint8_t* dst;
        if (bid < 2 * BATCH * NKV) {
            int id = bid - BATCH * NKV;
            srcb = V + (size_t)id * 32 * DIM;
            dst = ws + VOFF + (size_t)id * KT;
        } else {
            int wt = bid - 2 * BATCH * NKV;
            srcb = W + (size_t)wt * 32 * DIM;
            dst = ws + WOFF + (size_t)wt * KT;
        }
#pragma unroll
        for (int p = 0; p < 4; ++p) {
            int d = p * 4 + fb;
            float v[8];
#pragma unroll
            for (int j = 0; j < 8; ++j)
                v[j] = srcb[(size_t)(g * 8 + j) * DIM + d * 16 + nn];
            u32x4 u = {pack2(v[0], v[1]), pack2(v[2], v[3]),
                       pack2(v[4], v[5]), pack2(v[6], v[7])};
            *(u32x4*)(dst + d * 1024 + lane * 16) = u;
        }
    }
}

// smem phases: main loop: pbuf 4 waves x 2560 in [0,10240)
//              merge/epi: cbuf f32[32][256] [0,32768) | cbn bf16[32][264] [32768,49664)
//                         mws [49664,50176) | lws [50176,50688) | lgb [50688,50816)
#define SMEM_BYTES 50816

__device__ __forceinline__ void kv_step(
    bf16x8 (&qf)[2][8], bf16x8 (&kb)[16], bf16x8 (&kbn)[16],
    f32x4 (&ctx)[2][16], float (&m)[2][4], float (&l)[2][4],
    const uint8_t* vf, const uint8_t* kfn, uint8_t* pbuf, int g, int nn) {
    bf16x8 vvA[8], vvB[8];
#pragma unroll
    for (int d = 0; d < 8; ++d) vvA[d] = *(const bf16x8*)(vf + d * 1024);   // land under QK
    f32x4 s[2][2];
#pragma unroll
    for (int rt = 0; rt < 2; ++rt)
#pragma unroll
        for (int t2 = 0; t2 < 2; ++t2) {
            f32x4 acc = (f32x4){0.f, 0.f, 0.f, 0.f};
#pragma unroll
            for (int kk = 0; kk < 8; ++kk)
                acc = __builtin_amdgcn_mfma_f32_16x16x32_bf16(qf[rt][kk], kb[t2 * 8 + kk], acc, 0, 0, 0);
            s[rt][t2] = acc;
        }
#pragma unroll
    for (int f = 0; f < 16; ++f) kbn[f] = *(const bf16x8*)(kfn + f * 1024); // prefetch next K
#pragma unroll
    for (int d = 0; d < 8; ++d) vvB[d] = *(const bf16x8*)(vf + (d + 8) * 1024);
    // defer-max online softmax (S already in log2 units)
    int need = 0;
    float smax[2][4];
#pragma unroll
    for (int rt = 0; rt < 2; ++rt)
#pragma unroll
        for (int r = 0; r < 4; ++r) {
            smax[rt][r] = fmaxf(s[rt][0][r], s[rt][1][r]);
            need |= (smax[rt][r] > m[rt][r] + 8.0f);
        }
    if (__any(need)) {                          // taken ~only on first tile
#pragma unroll
        for (int rt = 0; rt < 2; ++rt)
#pragma unroll
            for (int r = 0; r < 4; ++r) {
                float v = smax[rt][r];
                v = fmaxf(v, __shfl_xor(v, 1));
                v = fmaxf(v, __shfl_xor(v, 2));
                v = fmaxf(v, __shfl_xor(v, 4));
                v = fmaxf(v, __shfl_xor(v, 8));
                float mn = fmaxf(m[rt][r], v);
                float sc0 = exp2_fast(m[rt][r] - mn);
                m[rt][r] = mn;
                l[rt][r] *= sc0;
#pragma unroll
                for (int d = 0; d < 16; ++d) ctx[rt][d][r] *= sc0;
            }
    }
#pragma unroll
    for (int rt = 0; rt < 2; ++rt) {
        uint8_t* pb = pbuf + rt * 1280;
#pragma unroll
        for (int r = 0; r < 4; ++r) {
            float p0 = exp2_fast(s[rt][0][r] - m[rt][r]);   // bounded by 2^8
            float p1 = exp2_fast(s[rt][1][r] - m[rt][r]);
            l[rt][r] += p0 + p1;
            unsigned pk = cvt_pk_bf16(p0, p1);
            *(unsigned short*)(pb + (g * 4 + r) * 80 + nn * 2)      = (unsigned short)pk;
            *(unsigned short*)(pb + (g * 4 + r) * 80 + 32 + nn * 2) = (unsigned short)(pk >> 16);
        }
    }
    bf16x8 pa0 = *(const bf16x8*)(pbuf + nn * 80 + g * 16);
    bf16x8 pa1 = *(const bf16x8*)(pbuf + 1280 + nn * 80 + g * 16);
#pragma unroll
    for (int d = 0; d < 16; ++d) {
        bf16x8 vv = (d < 8) ? vvA[d & 7] : vvB[d & 7];
        ctx[0][d] = __builtin_amdgcn_mfma_f32_16x16x32_bf16(pa0, vv, ctx[0][d], 0, 0, 0);
        ctx[1][d] = __builtin_amdgcn_mfma_f32_16x16x32_bf16(pa1, vv, ctx[1][d], 0, 0, 0);
    }
}

__launch_bounds__(256)
__global__ void attn_main(const float* __restrict__ Q, const float* __restrict__ bias,
                          const uint8_t* __restrict__ ws, float* __restrict__ out) {
    __shared__ __align__(16) uint8_t smem[SMEM_BYTES];
    float* cbuf = (float*)smem;                  // phase 2 (overlaps pbuf region)
    uint8_t* cbn = smem + 32768;
    float* mws = (float*)(smem + 49664);
    float* lws = (float*)(smem + 50176);
    float* lgb = (float*)(smem + 50688);

    const int tid = threadIdx.x;
    const int wid = tid >> 6, lane = tid & 63, g = lane >> 4, nn = lane & 15;
    uint8_t* pbuf = smem + wid * 2560;           // phase 1: per-wave 2 rowtiles x 1280
    const int b = blockIdx.x & 7, qg = blockIdx.x >> 3;   // batch -> XCD affinity
    const int q0 = qg * 32;

    // Q fragments for 2 row-tiles (A-layout: row = nn, k = g*8 + j)
    bf16x8 qf[2][8];
#pragma unroll
    for (int rt = 0; rt < 2; ++rt) {
        const float* qrow = Q + ((size_t)b * SEQ + q0 + rt * 16 + nn) * DIM + g * 8;
#pragma unroll
        for (int t8 = 0; t8 < 8; ++t8) {
            float4 a = *(const float4*)(qrow + t8 * 32);
            float4 c = *(const float4*)(qrow + t8 * 32 + 4);
            union { bf16x8 v; unsigned u[4]; } tmp;
            tmp.u[0] = pack2(a.x, a.y); tmp.u[1] = pack2(a.z, a.w);
            tmp.u[2] = pack2(c.x, c.y); tmp.u[3] = pack2(c.z, c.w);
            qf[rt][t8] = tmp.v;
        }
    }

    f32x4 ctx[2][16];
#pragma unroll
    for (int rt = 0; rt < 2; ++rt)
#pragma unroll
        for (int d = 0; d < 16; ++d) ctx[rt][d] = (f32x4){0.f, 0.f, 0.f, 0.f};
    float m[2][4] = {{-1e30f, -1e30f, -1e30f, -1e30f}, {-1e30f, -1e30f, -1e30f, -1e30f}};
    float l[2][4] = {{0.f, 0.f, 0.f, 0.f}, {0.f, 0.f, 0.f, 0.f}};

    // wave wid owns kv tiles [wid*16, wid*16+16); no barriers in the main loop
    const uint8_t* kws = ws + ((size_t)b * NKV + wid * 16) * KT + lane * 16;
    const uint8_t* vws = ws + VOFF + ((size_t)b * NKV + wid * 16) * KT + lane * 16;

    bf16x8 kbA[16], kbB[16];
#pragma unroll
    for (int f = 0; f < 16; ++f) kbA[f] = *(const bf16x8*)(kws + f * 1024);

    for (int t = 0; t < 16; t += 2) {
        kv_step(qf, kbA, kbB, ctx, m, l, vws + (size_t)t * KT,
                kws + (size_t)(t + 1) * KT, pbuf, g, nn);
        int tn = (t + 2 < 16) ? t + 2 : 15;
        kv_step(qf, kbB, kbA, ctx, m, l, vws + (size_t)(t + 1) * KT,
                kws + (size_t)tn * KT, pbuf, g, nn);
    }

    // reduce per-lane l partials across the 16 kv lanes (once)
#pragma unroll
    for (int rt = 0; rt < 2; ++rt)
#pragma unroll
        for (int r = 0; r < 4; ++r) {
            float v = l[rt][r];
            v += __shfl_xor(v, 1);
            v += __shfl_xor(v, 2);
            v += __shfl_xor(v, 4);
            v += __shfl_xor(v, 8);
            l[rt][r] = v;
        }

    // ---- merge the 4 KV-split partials ----
    if (nn == 0) {
#pragma unroll
        for (int rt = 0; rt < 2; ++rt)
#pragma unroll
            for (int r = 0; r < 4; ++r) {
                mws[wid * 32 + rt * 16 + g * 4 + r] = m[rt][r];
                lws[wid * 32 + rt * 16 + g * 4 + r] = l[rt][r];
            }
    }
    __syncthreads();
    float sc[2][4];
#pragma unroll
    for (int rt = 0; rt < 2; ++rt)
#pragma unroll
        for (int r = 0; r < 4; ++r) {
            int row = rt * 16 + g * 4 + r;
            float m0 = mws[row], m1 = mws[32 + row], m2 = mws[64 + row], m3 = mws[96 + row];
            float mg = fmaxf(fmaxf(m0, m1), fmaxf(m2, m3));
            float lg = lws[row]      * exp2_fast(m0 - mg)
                     + lws[32 + row] * exp2_fast(m1 - mg)
                     + lws[64 + row] * exp2_fast(m2 - mg)
                     + lws[96 + row] * exp2_fast(m3 - mg);
            sc[rt][r] = exp2_fast(m[rt][r] - mg);
            if (wid == 0 && nn == 0) lgb[row] = lg;
        }
    // sequential accumulate into cbuf (w=0 stores; deterministic)
    for (int w = 0; w < 4; ++w) {
        if (wid == w) {
#pragma unroll
            for (int rt = 0; rt < 2; ++rt)
#pragma unroll
                for (int d = 0; d < 16; ++d)
#pragma unroll
                    for (int r = 0; r < 4; ++r) {
                        float* p = cbuf + (size_t)(rt * 16 + g * 4 + r) * 256 + d * 16 + nn;
                        float v = ctx[rt][d][r] * sc[rt][r];
                        if (w == 0) *p = v; else *p += v;
                    }
        }
        __syncthreads();
    }
    // normalize + convert to bf16 image cbn[32][264]
    {
        int row = tid >> 3, c0 = (tid & 7) * 32;
        float il = 1.0f / lgb[row];
        const float* src = cbuf + (size_t)row * 256 + c0;
        uint8_t* dp = cbn + (size_t)row * 528 + c0 * 2;
#pragma unroll
        for (int i = 0; i < 4; ++i) {
            f32x4 a = *(const f32x4*)(src + i * 8);
            f32x4 c = *(const f32x4*)(src + i * 8 + 4);
            u32x4 u = {pack2(a[0] * il, a[1] * il), pack2(a[2] * il, a[3] * il),
                       pack2(c[0] * il, c[1] * il), pack2(c[2] * il, c[3] * il)};
            *(u32x4*)(dp + i * 16) = u;
        }
    }
    __syncthreads();

    // ---- epilogue: out = [ctxn, Q] @ W + b; wave wid owns output cols [wid*64, wid*64+64) ----
    f32x4 oacc[2][4];
#pragma unroll
    for (int rt = 0; rt < 2; ++rt)
#pragma unroll
        for (int dd = 0; dd < 4; ++dd) oacc[rt][dd] = (f32x4){0.f, 0.f, 0.f, 0.f};
    const uint8_t* wws = ws + WOFF + lane * 16;
    for (int wt = 0; wt < NWT; ++wt) {
        bf16x8 af[2];
#pragma unroll
        for (int rt = 0; rt < 2; ++rt) {
            if (wt < 8) af[rt] = *(const bf16x8*)(cbn + (size_t)(rt * 16 + nn) * 528 + wt * 64 + g * 16);
            else        af[rt] = qf[rt][wt - 8];
        }
#pragma unroll
        for (int dd = 0; dd < 4; ++dd) {
            bf16x8 wf = *(const bf16x8*)(wws + (size_t)(wt * 16 + wid * 4 + dd) * 1024);
#pragma unroll
            for (int rt = 0; rt < 2; ++rt)
                oacc[rt][dd] = __builtin_amdgcn_mfma_f32_16x16x32_bf16(af[rt], wf, oacc[rt][dd], 0, 0, 0);
        }
    }
#pragma unroll
    for (int rt = 0; rt < 2; ++rt) {
        float* obase = out + ((size_t)b * SEQ + q0 + rt * 16) * DIM + wid * 64;
#pragma unroll
        for (int dd = 0; dd < 4; ++dd) {
            float bv = bias[wid * 64 + dd * 16 + nn];
#pragma unroll
            for (int r = 0; r < 4; ++r)
                obase[(size_t)(g * 4 + r) * DIM + dd * 16 + nn] = oacc[rt][dd][r] + bv;
        }
    }
}

extern "C" void kernel_launch(void* const* d_in, const int* in_sizes, int n_in,
                              void* d_out, int out_size, void* d_ws, size_t ws_size,
                              hipStream_t stream) {
    const float* Q    = (const float*)d_in[0];
    const float* K    = (const float*)d_in[1];
    const float* V    = (const float*)d_in[2];
    const float* W    = (const float*)d_in[3];
    const float* bias = (const float*)d_in[4];
    float* out = (float*)d_out;
    uint8_t* ws = (uint8_t*)d_ws;
    prep_frags<<<2 * BATCH * NKV + NWT, 256, 0, stream>>>(K, V, W, ws);
    attn_main<<<BATCH * SEQ / 32, 256, 0, stream>>>(Q, bias, ws, out);
}

// Round 7
// 101.688 us; speedup vs baseline: 1.5489x; 1.3459x over previous
//
#include <hip/hip_runtime.h>
#include <stdint.h>

#define BATCH 8
#define SEQ   2048
#define DIM   256
#define NKV   64                 // kv tiles of 32 rows
#define KT    16384              // fragment bytes per 32-row tile (16 frags x 1KB)
#define NWT   16                 // 512/32 W k-tiles
#define VOFF  ((size_t)BATCH * NKV * KT)          // 8 MiB
#define WOFF  (VOFF + (size_t)BATCH * NKV * KT)   // 16 MiB
#define C1    0.090215498f       // (1/16) * log2(e), folded into K at prep

typedef __attribute__((ext_vector_type(8))) short bf16x8;
typedef __attribute__((ext_vector_type(4))) float f32x4;
typedef __attribute__((ext_vector_type(4))) unsigned int u32x4;

__device__ __forceinline__ unsigned short f2bf(float x) {
    unsigned u = __float_as_uint(x);
    unsigned r = u + 0x7fffu + ((u >> 16) & 1u);     // RNE
    return (unsigned short)(r >> 16);
}
__device__ __forceinline__ unsigned pack2(float a, float b) {
    return (unsigned)f2bf(a) | ((unsigned)f2bf(b) << 16);
}
__device__ __forceinline__ float exp2_fast(float x) {   // raw v_exp_f32; args bounded above
    float r;
    asm("v_exp_f32 %0, %1" : "=v"(r) : "v"(x));
    return r;
}
__device__ __forceinline__ unsigned cvt_pk_bf16(float lo, float hi) {
    unsigned r;
    asm("v_cvt_pk_bf16_f32 %0, %1, %2" : "=v"(r) : "v"(lo), "v"(hi));
    return r;
}

// Fragment-major bf16 images; K pre-scaled by C1 so softmax needs no multiplies.
__global__ void prep_frags(const float* __restrict__ K, const float* __restrict__ V,
                           const float* __restrict__ W, uint8_t* __restrict__ ws) {
    const int bid = blockIdx.x, tid = threadIdx.x;
    const int lane = tid & 63, fb = tid >> 6, g = lane >> 4, nn = lane & 15;
    if (bid < BATCH * NKV) {
        const float* src = K + (size_t)bid * 32 * DIM;
        uint8_t* dst = ws + (size_t)bid * KT;
#pragma unroll
        for (int p = 0; p < 4; ++p) {
            int f = p * 4 + fb;
            int row = (f >> 3) * 16 + nn, col = (f & 7) * 32 + g * 8;
            float4 a = *(const float4*)(src + (size_t)row * DIM + col);
            float4 c = *(const float4*)(src + (size_t)row * DIM + col + 4);
            u32x4 u = {pack2(a.x * C1, a.y * C1), pack2(a.z * C1, a.w * C1),
                       pack2(c.x * C1, c.y * C1), pack2(c.z * C1, c.w * C1)};
            *(u32x4*)(dst + f * 1024 + lane * 16) = u;
        }
    } else {
        const float* srcb;
        uint8_t* dst;
        if (bid < 2 * BATCH * NKV) {
            int id = bid - BATCH * NKV;
            srcb = V + (size_t)id * 32 * DIM;
            dst = ws + VOFF + (size_t)id * KT;
        } else {
            int wt = bid - 2 * BATCH * NKV;
            srcb = W + (size_t)wt * 32 * DIM;
            dst = ws + WOFF + (size_t)wt * KT;
        }
#pragma unroll
        for (int p = 0; p < 4; ++p) {
            int d = p * 4 + fb;
            float v[8];
#pragma unroll
            for (int j = 0; j < 8; ++j)
                v[j] = srcb[(size_t)(g * 8 + j) * DIM + d * 16 + nn];
            u32x4 u = {pack2(v[0], v[1]), pack2(v[2], v[3]),
                       pack2(v[4], v[5]), pack2(v[6], v[7])};
            *(u32x4*)(dst + d * 1024 + lane * 16) = u;
        }
    }
}

// smem: pbuf 4x1280 [0,5120) | cbuf f32[16][256] [5120,21504) |
//       cbn bf16[16][264] [21504,29952) | mws[4][16] | lws[4][16] | lgb[16]
#define SMEM_BYTES 30528

__launch_bounds__(256, 2)
__global__ void attn_main(const float* __restrict__ Q, const float* __restrict__ bias,
                          const uint8_t* __restrict__ ws, float* __restrict__ out) {
    __shared__ __align__(16) uint8_t smem[SMEM_BYTES];
    float* cbuf = (float*)(smem + 5120);
    uint8_t* cbn = smem + 21504;
    float* mws = (float*)(smem + 29952);
    float* lws = (float*)(smem + 30208);
    float* lgb = (float*)(smem + 30464);

    const int tid = threadIdx.x;
    const int wid = tid >> 6, lane = tid & 63, g = lane >> 4, nn = lane & 15;
    uint8_t* pbuf = smem + wid * 1280;
    const int b = blockIdx.x & 7, qg = blockIdx.x >> 3;   // batch -> XCD affinity
    const int q0 = qg * 16;

    // zero the merge accumulator (visibility ordered by the first __syncthreads below)
    {
        f32x4 z = {0.f, 0.f, 0.f, 0.f};
        float* p = cbuf + tid * 16;
#pragma unroll
        for (int i = 0; i < 4; ++i) *(f32x4*)(p + i * 4) = z;
    }

    // Q fragments (A-layout: row = nn, k = t8*32 + g*8 + j); identical in all 4 waves
    bf16x8 qf[8];
    {
        const float* qrow = Q + ((size_t)b * SEQ + q0 + nn) * DIM + g * 8;
#pragma unroll
        for (int t8 = 0; t8 < 8; ++t8) {
            float4 a = *(const float4*)(qrow + t8 * 32);
            float4 c = *(const float4*)(qrow + t8 * 32 + 4);
            union { bf16x8 v; unsigned u[4]; } tmp;
            tmp.u[0] = pack2(a.x, a.y); tmp.u[1] = pack2(a.z, a.w);
            tmp.u[2] = pack2(c.x, c.y); tmp.u[3] = pack2(c.z, c.w);
            qf[t8] = tmp.v;
        }
    }

    f32x4 ctx[16];
#pragma unroll
    for (int d = 0; d < 16; ++d) ctx[d] = (f32x4){0.f, 0.f, 0.f, 0.f};
    float m[4] = {-1e30f, -1e30f, -1e30f, -1e30f};   // in log2 units (K pre-scaled by C1)
    float l[4] = {0.f, 0.f, 0.f, 0.f};               // per-lane partials; reduced after loop

    // each wave owns a contiguous KV quarter; no barriers in this loop
    const uint8_t* kws = ws + ((size_t)b * NKV + wid * 16) * KT + lane * 16;
    const uint8_t* vws = ws + VOFF + ((size_t)b * NKV + wid * 16) * KT + lane * 16;

    for (int t = 0; t < 16; ++t) {
        const uint8_t* kf = kws + (size_t)t * KT;
        const uint8_t* vf = vws + (size_t)t * KT;
        // early-issue first half of V: lands under the QK chain + softmax (T14)
        bf16x8 vvA[8];
#pragma unroll
        for (int d = 0; d < 8; ++d) vvA[d] = *(const bf16x8*)(vf + d * 1024);
        // ---- S = Q K^T (already in log2 units) ----
        f32x4 s[2];
#pragma unroll
        for (int t2 = 0; t2 < 2; ++t2) {
            bf16x8 kb[8];
#pragma unroll
            for (int kk = 0; kk < 8; ++kk)
                kb[kk] = *(const bf16x8*)(kf + (t2 * 8 + kk) * 1024);
            f32x4 acc = (f32x4){0.f, 0.f, 0.f, 0.f};
#pragma unroll
            for (int kk = 0; kk < 8; ++kk)
                acc = __builtin_amdgcn_mfma_f32_16x16x32_bf16(qf[kk], kb[kk], acc, 0, 0, 0);
            s[t2] = acc;
        }
        // early-issue second half of V: lands under softmax + P round-trip
        bf16x8 vvB[8];
#pragma unroll
        for (int d = 0; d < 8; ++d) vvB[d] = *(const bf16x8*)(vf + (d + 8) * 1024);
        // ---- defer-max online softmax: rescale only when a row max grows past THR=8 ----
        int need = 0;
        float smax[4];
#pragma unroll
        for (int r = 0; r < 4; ++r) {
            smax[r] = fmaxf(s[0][r], s[1][r]);
            need |= (smax[r] > m[r] + 8.0f);
        }
        if (__any(need)) {                          // wave-uniform; taken ~only at t=0
#pragma unroll
            for (int r = 0; r < 4; ++r) {
                float v = smax[r];
                v = fmaxf(v, __shfl_xor(v, 1));
                v = fmaxf(v, __shfl_xor(v, 2));
                v = fmaxf(v, __shfl_xor(v, 4));
                v = fmaxf(v, __shfl_xor(v, 8));
                float mn = fmaxf(m[r], v);
                float sc0 = exp2_fast(m[r] - mn);
                m[r] = mn;
                l[r] *= sc0;
#pragma unroll
                for (int d = 0; d < 16; ++d) ctx[d][r] *= sc0;
            }
        }
#pragma unroll
        for (int r = 0; r < 4; ++r) {
            float p0 = exp2_fast(s[0][r] - m[r]);   // bounded by 2^8
            float p1 = exp2_fast(s[1][r] - m[r]);
            l[r] += p0 + p1;
            unsigned pk = cvt_pk_bf16(p0, p1);
            *(unsigned short*)(pbuf + (g * 4 + r) * 80 + nn * 2)      = (unsigned short)pk;
            *(unsigned short*)(pbuf + (g * 4 + r) * 80 + 32 + nn * 2) = (unsigned short)(pk >> 16);
        }
        // ---- ctx += P V (P transposed via per-wave LDS; wave-internal, no barrier) ----
        bf16x8 pa = *(const bf16x8*)(pbuf + nn * 80 + g * 16);
#pragma unroll
        for (int d = 0; d < 8; ++d)
            ctx[d] = __builtin_amdgcn_mfma_f32_16x16x32_bf16(pa, vvA[d], ctx[d], 0, 0, 0);
#pragma unroll
        for (int d = 0; d < 8; ++d)
            ctx[d + 8] = __builtin_amdgcn_mfma_f32_16x16x32_bf16(pa, vvB[d], ctx[d + 8], 0, 0, 0);
    }

    // reduce per-lane l partials across the 16 kv lanes (once, not per tile)
#pragma unroll
    for (int r = 0; r < 4; ++r) {
        float v = l[r];
        v += __shfl_xor(v, 1);
        v += __shfl_xor(v, 2);
        v += __shfl_xor(v, 4);
        v += __shfl_xor(v, 8);
        l[r] = v;
    }

    // ---- merge the 4 KV-split partials (m, l, ctx) ----
    if (nn == 0) {
#pragma unroll
        for (int r = 0; r < 4; ++r) {
            mws[wid * 16 + g * 4 + r] = m[r];
            lws[wid * 16 + g * 4 + r] = l[r];
        }
    }
    __syncthreads();
    float sc[4];
#pragma unroll
    for (int r = 0; r < 4; ++r) {
        int row = g * 4 + r;
        float m0 = mws[row], m1 = mws[16 + row], m2 = mws[32 + row], m3 = mws[48 + row];
        float mg = fmaxf(fmaxf(m0, m1), fmaxf(m2, m3));
        float lg = lws[row]      * exp2_fast(m0 - mg)
                 + lws[16 + row] * exp2_fast(m1 - mg)
                 + lws[32 + row] * exp2_fast(m2 - mg)
                 + lws[48 + row] * exp2_fast(m3 - mg);
        sc[r] = exp2_fast(m[r] - mg);
        if (wid == 0 && nn == 0) lgb[row] = lg;
    }
    // sequential accumulate into cbuf (deterministic)
    for (int w = 0; w < 4; ++w) {
        if (wid == w) {
#pragma unroll
            for (int d = 0; d < 16; ++d) {
#pragma unroll
                for (int r = 0; r < 4; ++r) {
                    float* p = cbuf + (g * 4 + r) * 256 + d * 16 + nn;
                    *p += ctx[d][r] * sc[r];
                }
            }
        }
        __syncthreads();
    }
    // normalize + convert to bf16 image cbn[16][264]
    {
        int row = tid >> 4, c0 = (tid & 15) * 16;
        float il = 1.0f / lgb[row];
        const float* src = cbuf + row * 256 + c0;
        uint8_t* dp = cbn + row * 528 + c0 * 2;
#pragma unroll
        for (int i = 0; i < 2; ++i) {
            f32x4 a = *(const f32x4*)(src + i * 8);
            f32x4 c = *(const f32x4*)(src + i * 8 + 4);
            u32x4 u = {pack2(a[0] * il, a[1] * il), pack2(a[2] * il, a[3] * il),
                       pack2(c[0] * il, c[1] * il), pack2(c[2] * il, c[3] * il)};
            *(u32x4*)(dp + i * 16) = u;
        }
    }
    __syncthreads();

    // ---- epilogue: out = [ctxn, Q] @ W + b; wave wid owns output cols [wid*64, wid*64+64) ----
    f32x4 oacc[4];
#pragma unroll
    for (int dd = 0; dd < 4; ++dd) oacc[dd] = (f32x4){0.f, 0.f, 0.f, 0.f};
    const uint8_t* wws = ws + WOFF + lane * 16;
    for (int wt = 0; wt < NWT; ++wt) {
        bf16x8 af;
        if (wt < 8) af = *(const bf16x8*)(cbn + nn * 528 + wt * 64 + g * 16);
        else        af = qf[wt - 8];
#pragma unroll
        for (int dd = 0; dd < 4; ++dd) {
            bf16x8 wf = *(const bf16x8*)(wws + (size_t)(wt * 16 + wid * 4 + dd) * 1024);
            oacc[dd] = __builtin_amdgcn_mfma_f32_16x16x32_bf16(af, wf, oacc[dd], 0, 0, 0);
        }
    }
    float* obase = out + ((size_t)b * SEQ + q0) * DIM + wid * 64;
#pragma unroll
    for (int dd = 0; dd < 4; ++dd) {
        float bv = bias[wid * 64 + dd * 16 + nn];
#pragma unroll
        for (int r = 0; r < 4; ++r)
            obase[(size_t)(g * 4 + r) * DIM + dd * 16 + nn] = oacc[dd][r] + bv;
    }
}

extern "C" void kernel_launch(void* const* d_in, const int* in_sizes, int n_in,
                              void* d_out, int out_size, void* d_ws, size_t ws_size,
                              hipStream_t stream) {
    const float* Q    = (const float*)d_in[0];
    const float* K    = (const float*)d_in[1];
    const float* V    = (const float*)d_in[2];
    const float* W    = (const float*)d_in[3];
    const float* bias = (const float*)d_in[4];
    float* out = (float*)d_out;
    uint8_t* ws = (uint8_t*)d_ws;
    prep_frags<<<2 * BATCH * NKV + NWT, 256, 0, stream>>>(K, V, W, ws);
    attn_main<<<BATCH * SEQ / 16, 256, 0, stream>>>(Q, bias, ws, out);
}

// Round 8
// 86.851 us; speedup vs baseline: 1.8135x; 1.1708x over previous
//
#include <hip/hip_runtime.h>
#include <stdint.h>

#define BATCH 8
#define SEQ   2048
#define DIM   256
#define NKV   64                 // kv tiles of 32 rows
#define KT8   8192               // fp8 K/V tile: 8 pair-frags x 1KB
#define NWT   16
#define WT    16384              // bf16 W tile: 16 frags x 1KB
#define VOFF  ((size_t)BATCH * NKV * KT8)          // 4 MiB
#define WOFF  (VOFF + (size_t)BATCH * NKV * KT8)   // 8 MiB
#define C1    0.090215498f       // (1/16) * log2(e)
#define THRRAW 88.6766f          // 8 / C1  (defer-max threshold in raw S units)

typedef __attribute__((ext_vector_type(8))) short bf16x8;
typedef __attribute__((ext_vector_type(4))) float f32x4;
typedef __attribute__((ext_vector_type(4))) unsigned int u32x4;

__device__ __forceinline__ unsigned short f2bf(float x) {
    unsigned u = __float_as_uint(x);
    unsigned r = u + 0x7fffu + ((u >> 16) & 1u);     // RNE
    return (unsigned short)(r >> 16);
}
__device__ __forceinline__ unsigned pack2(float a, float b) {
    return (unsigned)f2bf(a) | ((unsigned)f2bf(b) << 16);
}
__device__ __forceinline__ float exp2_fast(float x) {
    float r;
    asm("v_exp_f32 %0, %1" : "=v"(r) : "v"(x));
    return r;
}
// pack 4 f32 -> 4 OCP e4m3 bytes in one u32
__device__ __forceinline__ unsigned pk8x4(float a, float b, float c, float d) {
    unsigned u = __builtin_amdgcn_cvt_pk_fp8_f32(a, b, 0, false);
    return __builtin_amdgcn_cvt_pk_fp8_f32(c, d, u, true);
}
__device__ __forceinline__ long long mk64(unsigned lo, unsigned hi) {
    return (long long)(((unsigned long long)hi << 32) | lo);
}
__device__ __forceinline__ unsigned bperm(int srclane, unsigned v) {
    return (unsigned)__builtin_amdgcn_ds_bpermute(srclane * 4, (int)v);
}

// K: fp8 swapped-A pair-frags. pair pr=(t2,kk2): lane(g,nn) 16B =
//   fp8 K[t*32+t2*16+nn][kk2*64 + g*8 + 0..7]  ||  [... + 32 + 0..7]
// V: fp8 B pair-frags. pair d2: lane(g,nn) 16B =
//   fp8 V[t*32+g*8+j][d2*32+nn] j=0..7  ||  [d2*32+16+nn]
// W: bf16 frag-major (unchanged layout), frag d: lane -> W[wt*32+g*8+j][d*16+nn]
__global__ void prep_frags(const float* __restrict__ K, const float* __restrict__ V,
                           const float* __restrict__ W, uint8_t* __restrict__ ws) {
    const int bid = blockIdx.x, tid = threadIdx.x;
    const int lane = tid & 63, fb = tid >> 6, g = lane >> 4, nn = lane & 15;
    if (bid < BATCH * NKV) {
        const float* src = K + (size_t)bid * 32 * DIM;
        uint8_t* dst = ws + (size_t)bid * KT8;
#pragma unroll
        for (int p = 0; p < 2; ++p) {
            int pr = p * 4 + fb, t2 = pr >> 2, kk2 = pr & 3;
            const float* rp = src + (size_t)(t2 * 16 + nn) * DIM + kk2 * 64 + g * 8;
            float4 a  = *(const float4*)(rp);
            float4 a2 = *(const float4*)(rp + 4);
            float4 c  = *(const float4*)(rp + 32);
            float4 c2 = *(const float4*)(rp + 36);
            u32x4 u = {pk8x4(a.x, a.y, a.z, a.w), pk8x4(a2.x, a2.y, a2.z, a2.w),
                       pk8x4(c.x, c.y, c.z, c.w), pk8x4(c2.x, c2.y, c2.z, c2.w)};
            *(u32x4*)(dst + pr * 1024 + lane * 16) = u;
        }
    } else if (bid < 2 * BATCH * NKV) {
        const int id = bid - BATCH * NKV;
        const float* src = V + (size_t)id * 32 * DIM;
        uint8_t* dst = ws + VOFF + (size_t)id * KT8;
#pragma unroll
        for (int p = 0; p < 2; ++p) {
            int pr = p * 4 + fb;
            float v0[8], v1[8];
#pragma unroll
            for (int j = 0; j < 8; ++j) {
                v0[j] = src[(size_t)(g * 8 + j) * DIM + pr * 32 + nn];
                v1[j] = src[(size_t)(g * 8 + j) * DIM + pr * 32 + 16 + nn];
            }
            u32x4 u = {pk8x4(v0[0], v0[1], v0[2], v0[3]), pk8x4(v0[4], v0[5], v0[6], v0[7]),
                       pk8x4(v1[0], v1[1], v1[2], v1[3]), pk8x4(v1[4], v1[5], v1[6], v1[7])};
            *(u32x4*)(dst + pr * 1024 + lane * 16) = u;
        }
    } else {
        const int wt = bid - 2 * BATCH * NKV;
        const float* src = W + (size_t)wt * 32 * DIM;
        uint8_t* dst = ws + WOFF + (size_t)wt * WT;
#pragma unroll
        for (int p = 0; p < 4; ++p) {
            int d = p * 4 + fb;
            float v[8];
#pragma unroll
            for (int j = 0; j < 8; ++j)
                v[j] = src[(size_t)(g * 8 + j) * DIM + d * 16 + nn];
            u32x4 u = {pack2(v[0], v[1]), pack2(v[2], v[3]),
                       pack2(v[4], v[5]), pack2(v[6], v[7])};
            *(u32x4*)(dst + d * 1024 + lane * 16) = u;
        }
    }
}

// smem: cbuf f32[16][256] [0,16384) | cbn bf16[16][264] [16384,24832)
//       mws [24832,25088) | lws [25088,25344) | lgb [25344,25408)
#define SMEM_BYTES 25408

__launch_bounds__(256, 2)
__global__ void attn_main(const float* __restrict__ Q, const float* __restrict__ bias,
                          const uint8_t* __restrict__ ws, float* __restrict__ out) {
    __shared__ __align__(16) uint8_t smem[SMEM_BYTES];
    float* cbuf = (float*)smem;
    uint8_t* cbn = smem + 16384;
    float* mws = (float*)(smem + 24832);
    float* lws = (float*)(smem + 25088);
    float* lgb = (float*)(smem + 25344);

    const int tid = threadIdx.x;
    const int wid = tid >> 6, lane = tid & 63, g = lane >> 4, nn = lane & 15;
    const int b = blockIdx.x & 7, qg = blockIdx.x >> 3;   // batch -> XCD affinity
    const int q0 = qg * 16;

    {   // zero merge accumulator (ordered by the first __syncthreads)
        f32x4 z = {0.f, 0.f, 0.f, 0.f};
        float* p = cbuf + tid * 16;
#pragma unroll
        for (int i = 0; i < 4; ++i) *(f32x4*)(p + i * 4) = z;
    }

    // Q as fp8 B-frags for swapped QK (col=q=nn, k = d = t8*32 + g*8 + j)
    const float* qrow = Q + ((size_t)b * SEQ + q0 + nn) * DIM + g * 8;
    long long qp[8];
#pragma unroll
    for (int t8 = 0; t8 < 8; ++t8) {
        float4 a = *(const float4*)(qrow + t8 * 32);
        float4 c = *(const float4*)(qrow + t8 * 32 + 4);
        qp[t8] = mk64(pk8x4(a.x, a.y, a.z, a.w), pk8x4(c.x, c.y, c.z, c.w));
    }

    f32x4 ctx[16];
#pragma unroll
    for (int d = 0; d < 16; ++d) ctx[d] = (f32x4){0.f, 0.f, 0.f, 0.f};
    float m = -3e38f, mc = 0.f, l = 0.f;     // per-lane: q = nn (raw S units)

    const uint8_t* kws = ws + ((size_t)b * NKV + wid * 16) * KT8 + lane * 16;
    const uint8_t* vws = ws + VOFF + ((size_t)b * NKV + wid * 16) * KT8 + lane * 16;

    for (int t = 0; t < 16; ++t) {
        const uint8_t* kf = kws + (size_t)t * KT8;
        const uint8_t* vf = vws + (size_t)t * KT8;
        u32x4 vp[4];
#pragma unroll
        for (int i = 0; i < 4; ++i) vp[i] = *(const u32x4*)(vf + i * 1024);   // early V
        u32x4 kp[8];
#pragma unroll
        for (int i = 0; i < 8; ++i) kp[i] = *(const u32x4*)(kf + i * 1024);
        // ---- S^T = K Q : D[kv=4g+r (+16*t2)][q=nn] ----
        f32x4 s0 = (f32x4){0.f, 0.f, 0.f, 0.f}, s1 = s0;
#pragma unroll
        for (int kk = 0; kk < 8; ++kk) {
            int i = kk >> 1, h = kk & 1;
            s0 = __builtin_amdgcn_mfma_f32_16x16x32_fp8_fp8(
                     mk64(kp[i][2 * h], kp[i][2 * h + 1]), qp[kk], s0, 0, 0, 0);
            s1 = __builtin_amdgcn_mfma_f32_16x16x32_fp8_fp8(
                     mk64(kp[4 + i][2 * h], kp[4 + i][2 * h + 1]), qp[kk], s1, 0, 0, 0);
        }
        u32x4 vp2[4];
#pragma unroll
        for (int i = 0; i < 4; ++i) vp2[i] = *(const u32x4*)(vf + (4 + i) * 1024);
        // ---- defer-max online softmax (per-lane scalar state, q = nn) ----
        float smax = fmaxf(fmaxf(fmaxf(s0[0], s0[1]), fmaxf(s0[2], s0[3])),
                           fmaxf(fmaxf(s1[0], s1[1]), fmaxf(s1[2], s1[3])));
        if (__any(smax > m + THRRAW)) {         // ~only at t=0
            float v = smax;
            v = fmaxf(v, __shfl_xor(v, 16));
            v = fmaxf(v, __shfl_xor(v, 32));
            float mn = fmaxf(m, v);
            float sc0 = exp2_fast((m - mn) * C1);
            m = mn; mc = m * C1; l *= sc0;
            float scr[4];
#pragma unroll
            for (int r = 0; r < 4; ++r)
                scr[r] = __uint_as_float(bperm(4 * g + r, __float_as_uint(sc0)));
#pragma unroll
            for (int d = 0; d < 16; ++d)
#pragma unroll
                for (int r = 0; r < 4; ++r) ctx[d][r] *= scr[r];
        }
        float p0[4], p1[4];
#pragma unroll
        for (int r = 0; r < 4; ++r) {
            p0[r] = exp2_fast(__builtin_fmaf(s0[r], C1, -mc));   // <= 2^8 < 448
            p1[r] = exp2_fast(__builtin_fmaf(s1[r], C1, -mc));
            l += p0[r] + p1[r];
        }
        unsigned pkA = pk8x4(p0[0], p0[1], p0[2], p0[3]);
        unsigned pkB = pk8x4(p1[0], p1[1], p1[2], p1[3]);
        // redistribute P to PV A-layout: lane(g,nn) needs kv = g*8..g*8+7 for q=nn
        int alo = ((2 * g) & 3) * 16 + nn;
        unsigned b00 = bperm(alo, pkA),      b01 = bperm(alo, pkB);
        unsigned b10 = bperm(alo + 16, pkA), b11 = bperm(alo + 16, pkB);
        long long A = mk64((g < 2) ? b00 : b01, (g < 2) ? b10 : b11);
        // ---- ctx += P V ----
#pragma unroll
        for (int i = 0; i < 4; ++i) {
            ctx[2 * i]     = __builtin_amdgcn_mfma_f32_16x16x32_fp8_fp8(
                                 A, mk64(vp[i][0], vp[i][1]), ctx[2 * i], 0, 0, 0);
            ctx[2 * i + 1] = __builtin_amdgcn_mfma_f32_16x16x32_fp8_fp8(
                                 A, mk64(vp[i][2], vp[i][3]), ctx[2 * i + 1], 0, 0, 0);
        }
#pragma unroll
        for (int i = 0; i < 4; ++i) {
            ctx[8 + 2 * i]     = __builtin_amdgcn_mfma_f32_16x16x32_fp8_fp8(
                                     A, mk64(vp2[i][0], vp2[i][1]), ctx[8 + 2 * i], 0, 0, 0);
            ctx[8 + 2 * i + 1] = __builtin_amdgcn_mfma_f32_16x16x32_fp8_fp8(
                                     A, mk64(vp2[i][2], vp2[i][3]), ctx[8 + 2 * i + 1], 0, 0, 0);
        }
    }

    // reduce l across the 4 lane-groups holding the same q
    l += __shfl_xor(l, 16);
    l += __shfl_xor(l, 32);

    if (lane < 16) { mws[wid * 16 + nn] = m; lws[wid * 16 + nn] = l; }
    __syncthreads();
    float sc[4];
#pragma unroll
    for (int r = 0; r < 4; ++r) {
        int row = g * 4 + r;
        float m0 = mws[row], m1 = mws[16 + row], m2 = mws[32 + row], m3 = mws[48 + row];
        float mg = fmaxf(fmaxf(m0, m1), fmaxf(m2, m3));
        float lg = lws[row]      * exp2_fast((m0 - mg) * C1)
                 + lws[16 + row] * exp2_fast((m1 - mg) * C1)
                 + lws[32 + row] * exp2_fast((m2 - mg) * C1)
                 + lws[48 + row] * exp2_fast((m3 - mg) * C1);
        sc[r] = exp2_fast((mws[wid * 16 + row] - mg) * C1);
        if (wid == 0 && nn == 0) lgb[row] = lg;
    }
    for (int w = 0; w < 4; ++w) {               // deterministic sequential merge
        if (wid == w) {
#pragma unroll
            for (int d = 0; d < 16; ++d)
#pragma unroll
                for (int r = 0; r < 4; ++r) {
                    float* p = cbuf + (g * 4 + r) * 256 + d * 16 + nn;
                    *p += ctx[d][r] * sc[r];
                }
        }
        __syncthreads();
    }
    {   // normalize + bf16 image cbn[16][264]
        int row = tid >> 4, c0 = (tid & 15) * 16;
        float il = 1.0f / lgb[row];
        const float* src = cbuf + row * 256 + c0;
        uint8_t* dp = cbn + row * 528 + c0 * 2;
#pragma unroll
        for (int i = 0; i < 2; ++i) {
            f32x4 a = *(const f32x4*)(src + i * 8);
            f32x4 c = *(const f32x4*)(src + i * 8 + 4);
            u32x4 u = {pack2(a[0] * il, a[1] * il), pack2(a[2] * il, a[3] * il),
                       pack2(c[0] * il, c[1] * il), pack2(c[2] * il, c[3] * il)};
            *(u32x4*)(dp + i * 16) = u;
        }
    }
    __syncthreads();

    // ---- epilogue: out = [ctxn, Q] @ W + b (bf16 path; Q reloaded) ----
    bf16x8 qe[8];
#pragma unroll
    for (int t8 = 0; t8 < 8; ++t8) {
        float4 a = *(const float4*)(qrow + t8 * 32);
        float4 c = *(const float4*)(qrow + t8 * 32 + 4);
        union { bf16x8 v; unsigned u[4]; } tmp;
        tmp.u[0] = pack2(a.x, a.y); tmp.u[1] = pack2(a.z, a.w);
        tmp.u[2] = pack2(c.x, c.y); tmp.u[3] = pack2(c.z, c.w);
        qe[t8] = tmp.v;
    }
    f32x4 oacc[4];
#pragma unroll
    for (int dd = 0; dd < 4; ++dd) oacc[dd] = (f32x4){0.f, 0.f, 0.f, 0.f};
    const uint8_t* wws = ws + WOFF + lane * 16;
    for (int wt = 0; wt < NWT; ++wt) {
        bf16x8 af;
        if (wt < 8) af = *(const bf16x8*)(cbn + nn * 528 + wt * 64 + g * 16);
        else        af = qe[wt - 8];
#pragma unroll
        for (int dd = 0; dd < 4; ++dd) {
            bf16x8 wf = *(const bf16x8*)(wws + (size_t)(wt * 16 + wid * 4 + dd) * 1024);
            oacc[dd] = __builtin_amdgcn_mfma_f32_16x16x32_bf16(af, wf, oacc[dd], 0, 0, 0);
        }
    }
    float* obase = out + ((size_t)b * SEQ + q0) * DIM + wid * 64;
#pragma unroll
    for (int dd = 0; dd < 4; ++dd) {
        float bv = bias[wid * 64 + dd * 16 + nn];
#pragma unroll
        for (int r = 0; r < 4; ++r)
            obase[(size_t)(g * 4 + r) * DIM + dd * 16 + nn] = oacc[dd][r] + bv;
    }
}

extern "C" void kernel_launch(void* const* d_in, const int* in_sizes, int n_in,
                              void* d_out, int out_size, void* d_ws, size_t ws_size,
                              hipStream_t stream) {
    const float* Q    = (const float*)d_in[0];
    const float* K    = (const float*)d_in[1];
    const float* V    = (const float*)d_in[2];
    const float* W    = (const float*)d_in[3];
    const float* bias = (const float*)d_in[4];
    float* out = (float*)d_out;
    uint8_t* ws = (uint8_t*)d_ws;
    prep_frags<<<2 * BATCH * NKV + NWT, 256, 0, stream>>>(K, V, W, ws);
    attn_main<<<BATCH * SEQ / 16, 256, 0, stream>>>(Q, bias, ws, out);
}

// Round 9
// 71.255 us; speedup vs baseline: 2.2104x; 1.2189x over previous
//
#include <hip/hip_runtime.h>
#include <stdint.h>

#define BATCH 8
#define SEQ   2048
#define DIM   256
#define NKV   64                 // kv tiles of 32 rows
#define KT8   8192               // fp8 K/V tile: 8 pair-frags x 1KB
#define NWT   16
#define WT    16384              // bf16 W tile: 16 frags x 1KB
#define VOFF  ((size_t)BATCH * NKV * KT8)          // 4 MiB
#define WOFF  (VOFF + (size_t)BATCH * NKV * KT8)   // 8 MiB
#define C1    0.090215498f       // (1/16) * log2(e)
#define THRRAW 88.6766f          // 8 / C1  (defer-max threshold in raw S units)

typedef __attribute__((ext_vector_type(8))) short bf16x8;
typedef __attribute__((ext_vector_type(4))) float f32x4;
typedef __attribute__((ext_vector_type(4))) unsigned int u32x4;

__device__ __forceinline__ unsigned short f2bf(float x) {
    unsigned u = __float_as_uint(x);
    unsigned r = u + 0x7fffu + ((u >> 16) & 1u);     // RNE
    return (unsigned short)(r >> 16);
}
__device__ __forceinline__ unsigned pack2(float a, float b) {
    return (unsigned)f2bf(a) | ((unsigned)f2bf(b) << 16);
}
__device__ __forceinline__ float exp2_fast(float x) {
    float r;
    asm("v_exp_f32 %0, %1" : "=v"(r) : "v"(x));
    return r;
}
__device__ __forceinline__ unsigned pk8x4(float a, float b, float c, float d) {
    unsigned u = __builtin_amdgcn_cvt_pk_fp8_f32(a, b, 0, false);
    return __builtin_amdgcn_cvt_pk_fp8_f32(c, d, u, true);
}
__device__ __forceinline__ long long mk64(unsigned lo, unsigned hi) {
    return (long long)(((unsigned long long)hi << 32) | lo);
}
__device__ __forceinline__ unsigned bperm(int srclane, unsigned v) {
    return (unsigned)__builtin_amdgcn_ds_bpermute(srclane * 4, (int)v);
}

// K: fp8 swapped-A pair-frags; V: fp8 B pair-frags; W: bf16 frag-major (as R8).
__global__ void prep_frags(const float* __restrict__ K, const float* __restrict__ V,
                           const float* __restrict__ W, uint8_t* __restrict__ ws) {
    const int bid = blockIdx.x, tid = threadIdx.x;
    const int lane = tid & 63, fb = tid >> 6, g = lane >> 4, nn = lane & 15;
    if (bid < BATCH * NKV) {
        const float* src = K + (size_t)bid * 32 * DIM;
        uint8_t* dst = ws + (size_t)bid * KT8;
#pragma unroll
        for (int p = 0; p < 2; ++p) {
            int pr = p * 4 + fb, t2 = pr >> 2, kk2 = pr & 3;
            const float* rp = src + (size_t)(t2 * 16 + nn) * DIM + kk2 * 64 + g * 8;
            float4 a  = *(const float4*)(rp);
            float4 a2 = *(const float4*)(rp + 4);
            float4 c  = *(const float4*)(rp + 32);
            float4 c2 = *(const float4*)(rp + 36);
            u32x4 u = {pk8x4(a.x, a.y, a.z, a.w), pk8x4(a2.x, a2.y, a2.z, a2.w),
                       pk8x4(c.x, c.y, c.z, c.w), pk8x4(c2.x, c2.y, c2.z, c2.w)};
            *(u32x4*)(dst + pr * 1024 + lane * 16) = u;
        }
    } else if (bid < 2 * BATCH * NKV) {
        const int id = bid - BATCH * NKV;
        const float* src = V + (size_t)id * 32 * DIM;
        uint8_t* dst = ws + VOFF + (size_t)id * KT8;
#pragma unroll
        for (int p = 0; p < 2; ++p) {
            int pr = p * 4 + fb;
            float v0[8], v1[8];
#pragma unroll
            for (int j = 0; j < 8; ++j) {
                v0[j] = src[(size_t)(g * 8 + j) * DIM + pr * 32 + nn];
                v1[j] = src[(size_t)(g * 8 + j) * DIM + pr * 32 + 16 + nn];
            }
            u32x4 u = {pk8x4(v0[0], v0[1], v0[2], v0[3]), pk8x4(v0[4], v0[5], v0[6], v0[7]),
                       pk8x4(v1[0], v1[1], v1[2], v1[3]), pk8x4(v1[4], v1[5], v1[6], v1[7])};
            *(u32x4*)(dst + pr * 1024 + lane * 16) = u;
        }
    } else {
        const int wt = bid - 2 * BATCH * NKV;
        const float* src = W + (size_t)wt * 32 * DIM;
        uint8_t* dst = ws + WOFF + (size_t)wt * WT;
#pragma unroll
        for (int p = 0; p < 4; ++p) {
            int d = p * 4 + fb;
            float v[8];
#pragma unroll
            for (int j = 0; j < 8; ++j)
                v[j] = src[(size_t)(g * 8 + j) * DIM + d * 16 + nn];
            u32x4 u = {pack2(v[0], v[1]), pack2(v[2], v[3]),
                       pack2(v[4], v[5]), pack2(v[6], v[7])};
            *(u32x4*)(dst + d * 1024 + lane * 16) = u;
        }
    }
}

// smem: cbuf f32[32][256] [0,32768) | cbn bf16[32][264] [32768,49664)
//       mws[4][32] [49664,50176) | lws [50176,50688) | lgb[32] [50688,50816)
#define SMEM_BYTES 50816

__launch_bounds__(256, 2)
__global__ void attn_main(const float* __restrict__ Q, const float* __restrict__ bias,
                          const uint8_t* __restrict__ ws, float* __restrict__ out) {
    __shared__ __align__(16) uint8_t smem[SMEM_BYTES];
    float* cbuf = (float*)smem;
    uint8_t* cbn = smem + 32768;
    float* mws = (float*)(smem + 49664);
    float* lws = (float*)(smem + 50176);
    float* lgb = (float*)(smem + 50688);

    const int tid = threadIdx.x;
    const int wid = tid >> 6, lane = tid & 63, g = lane >> 4, nn = lane & 15;
    const int b = blockIdx.x & 7, qg = blockIdx.x >> 3;   // batch -> XCD affinity
    const int q0 = qg * 32;

    {   // zero merge accumulator (ordered by the first __syncthreads)
        f32x4 z = {0.f, 0.f, 0.f, 0.f};
        float* p = cbuf + tid * 32;
#pragma unroll
        for (int i = 0; i < 8; ++i) *(f32x4*)(p + i * 4) = z;
    }

    // Q as fp8 B-frags for swapped QK, 2 q-subtiles (col=q=nn, k = t8*32 + g*8 + j)
    const float* qbase = Q + ((size_t)b * SEQ + q0 + nn) * DIM + g * 8;
    long long qp[2][8];
#pragma unroll
    for (int rt = 0; rt < 2; ++rt)
#pragma unroll
        for (int t8 = 0; t8 < 8; ++t8) {
            const float* rp = qbase + (size_t)rt * 16 * DIM + t8 * 32;
            float4 a = *(const float4*)(rp);
            float4 c = *(const float4*)(rp + 4);
            qp[rt][t8] = mk64(pk8x4(a.x, a.y, a.z, a.w), pk8x4(c.x, c.y, c.z, c.w));
        }

    f32x4 ctx[2][16];
#pragma unroll
    for (int rt = 0; rt < 2; ++rt)
#pragma unroll
        for (int d = 0; d < 16; ++d) ctx[rt][d] = (f32x4){0.f, 0.f, 0.f, 0.f};
    float m[2] = {-3e38f, -3e38f}, mc[2] = {0.f, 0.f}, l[2] = {0.f, 0.f};

    const uint8_t* kws = ws + ((size_t)b * NKV + wid * 16) * KT8 + lane * 16;
    const uint8_t* vws = ws + VOFF + ((size_t)b * NKV + wid * 16) * KT8 + lane * 16;

    for (int t = 0; t < 16; ++t) {
        const uint8_t* kf = kws + (size_t)t * KT8;
        const uint8_t* vf = vws + (size_t)t * KT8;
        u32x4 kp[8];
#pragma unroll
        for (int i = 0; i < 8; ++i) kp[i] = *(const u32x4*)(kf + i * 1024);
        // ---- S^T = K Q for both q-subtiles (K frags shared) ----
        f32x4 s[2][2];
#pragma unroll
        for (int rt = 0; rt < 2; ++rt) { s[rt][0] = (f32x4){0.f,0.f,0.f,0.f}; s[rt][1] = s[rt][0]; }
#pragma unroll
        for (int kk = 0; kk < 8; ++kk) {
            int i = kk >> 1, h = kk & 1;
            long long ka = mk64(kp[i][2 * h], kp[i][2 * h + 1]);
            long long kb2 = mk64(kp[4 + i][2 * h], kp[4 + i][2 * h + 1]);
#pragma unroll
            for (int rt = 0; rt < 2; ++rt) {
                s[rt][0] = __builtin_amdgcn_mfma_f32_16x16x32_fp8_fp8(ka,  qp[rt][kk], s[rt][0], 0, 0, 0);
                s[rt][1] = __builtin_amdgcn_mfma_f32_16x16x32_fp8_fp8(kb2, qp[rt][kk], s[rt][1], 0, 0, 0);
            }
        }
        // ---- defer-max online softmax (per-lane scalar state, q = nn) ----
        float smax[2];
        int need = 0;
#pragma unroll
        for (int rt = 0; rt < 2; ++rt) {
            smax[rt] = fmaxf(fmaxf(fmaxf(s[rt][0][0], s[rt][0][1]), fmaxf(s[rt][0][2], s[rt][0][3])),
                             fmaxf(fmaxf(s[rt][1][0], s[rt][1][1]), fmaxf(s[rt][1][2], s[rt][1][3])));
            need |= (smax[rt] > m[rt] + THRRAW);
        }
        if (__any(need)) {                          // ~only at t=0
#pragma unroll
            for (int rt = 0; rt < 2; ++rt) {
                float v = smax[rt];
                v = fmaxf(v, __shfl_xor(v, 16));
                v = fmaxf(v, __shfl_xor(v, 32));
                float mn = fmaxf(m[rt], v);
                float sc0 = exp2_fast((m[rt] - mn) * C1);
                m[rt] = mn; mc[rt] = mn * C1; l[rt] *= sc0;
                float scr[4];
#pragma unroll
                for (int r = 0; r < 4; ++r)
                    scr[r] = __uint_as_float(bperm(4 * g + r, __float_as_uint(sc0)));
#pragma unroll
                for (int d = 0; d < 16; ++d)
#pragma unroll
                    for (int r = 0; r < 4; ++r) ctx[rt][d][r] *= scr[r];
            }
        }
        unsigned pkA[2], pkB[2];
#pragma unroll
        for (int rt = 0; rt < 2; ++rt) {
            float p0[4], p1[4];
#pragma unroll
            for (int r = 0; r < 4; ++r) {
                p0[r] = exp2_fast(__builtin_fmaf(s[rt][0][r], C1, -mc[rt]));   // <= 2^8 < 448
                p1[r] = exp2_fast(__builtin_fmaf(s[rt][1][r], C1, -mc[rt]));
                l[rt] += p0[r] + p1[r];
            }
            pkA[rt] = pk8x4(p0[0], p0[1], p0[2], p0[3]);
            pkB[rt] = pk8x4(p1[0], p1[1], p1[2], p1[3]);
        }
        // V loads issued here: latency hides under the bperm block
        u32x4 vp[8];
#pragma unroll
        for (int i = 0; i < 8; ++i) vp[i] = *(const u32x4*)(vf + i * 1024);
        // redistribute P to PV A-layout: lane(g,nn) needs kv = g*8..g*8+7 for q=nn
        long long A[2];
        {
            int alo = ((2 * g) & 3) * 16 + nn;
#pragma unroll
            for (int rt = 0; rt < 2; ++rt) {
                unsigned b00 = bperm(alo, pkA[rt]),      b01 = bperm(alo, pkB[rt]);
                unsigned b10 = bperm(alo + 16, pkA[rt]), b11 = bperm(alo + 16, pkB[rt]);
                A[rt] = mk64((g < 2) ? b00 : b01, (g < 2) ? b10 : b11);
            }
        }
        // ---- ctx += P V (V frags shared across subtiles) ----
#pragma unroll
        for (int i = 0; i < 4; ++i) {
            long long v0 = mk64(vp[i][0], vp[i][1]), v1 = mk64(vp[i][2], vp[i][3]);
#pragma unroll
            for (int rt = 0; rt < 2; ++rt) {
                ctx[rt][2 * i]     = __builtin_amdgcn_mfma_f32_16x16x32_fp8_fp8(A[rt], v0, ctx[rt][2 * i], 0, 0, 0);
                ctx[rt][2 * i + 1] = __builtin_amdgcn_mfma_f32_16x16x32_fp8_fp8(A[rt], v1, ctx[rt][2 * i + 1], 0, 0, 0);
            }
        }
#pragma unroll
        for (int i = 0; i < 4; ++i) {
            long long v0 = mk64(vp[4 + i][0], vp[4 + i][1]), v1 = mk64(vp[4 + i][2], vp[4 + i][3]);
#pragma unroll
            for (int rt = 0; rt < 2; ++rt) {
                ctx[rt][8 + 2 * i]     = __builtin_amdgcn_mfma_f32_16x16x32_fp8_fp8(A[rt], v0, ctx[rt][8 + 2 * i], 0, 0, 0);
                ctx[rt][8 + 2 * i + 1] = __builtin_amdgcn_mfma_f32_16x16x32_fp8_fp8(A[rt], v1, ctx[rt][8 + 2 * i + 1], 0, 0, 0);
            }
        }
    }

    // reduce l across the 4 lane-groups holding the same q
#pragma unroll
    for (int rt = 0; rt < 2; ++rt) {
        l[rt] += __shfl_xor(l[rt], 16);
        l[rt] += __shfl_xor(l[rt], 32);
    }

    if (lane < 16) {
#pragma unroll
        for (int rt = 0; rt < 2; ++rt) {
            mws[wid * 32 + rt * 16 + nn] = m[rt];
            lws[wid * 32 + rt * 16 + nn] = l[rt];
        }
    }
    __syncthreads();
    float sc[2][4];
#pragma unroll
    for (int rt = 0; rt < 2; ++rt)
#pragma unroll
        for (int r = 0; r < 4; ++r) {
            int row = rt * 16 + g * 4 + r;
            float m0 = mws[row], m1 = mws[32 + row], m2 = mws[64 + row], m3 = mws[96 + row];
            float mg = fmaxf(fmaxf(m0, m1), fmaxf(m2, m3));
            float lg = lws[row]      * exp2_fast((m0 - mg) * C1)
                     + lws[32 + row] * exp2_fast((m1 - mg) * C1)
                     + lws[64 + row] * exp2_fast((m2 - mg) * C1)
                     + lws[96 + row] * exp2_fast((m3 - mg) * C1);
            sc[rt][r] = exp2_fast((mws[wid * 32 + row] - mg) * C1);
            if (wid == 0 && nn == 0) lgb[row] = lg;
        }
    for (int w = 0; w < 4; ++w) {               // deterministic sequential merge
        if (wid == w) {
#pragma unroll
            for (int rt = 0; rt < 2; ++rt)
#pragma unroll
                for (int d = 0; d < 16; ++d)
#pragma unroll
                    for (int r = 0; r < 4; ++r) {
                        float* p = cbuf + (size_t)(rt * 16 + g * 4 + r) * 256 + d * 16 + nn;
                        *p += ctx[rt][d][r] * sc[rt][r];
                    }
        }
        __syncthreads();
    }
    {   // normalize + bf16 image cbn[32][264]
        int row = tid >> 3, c0 = (tid & 7) * 32;
        float il = 1.0f / lgb[row];
        const float* src = cbuf + (size_t)row * 256 + c0;
        uint8_t* dp = cbn + (size_t)row * 528 + c0 * 2;
#pragma unroll
        for (int i = 0; i < 4; ++i) {
            f32x4 a = *(const f32x4*)(src + i * 8);
            f32x4 c = *(const f32x4*)(src + i * 8 + 4);
            u32x4 u = {pack2(a[0] * il, a[1] * il), pack2(a[2] * il, a[3] * il),
                       pack2(c[0] * il, c[1] * il), pack2(c[2] * il, c[3] * il)};
            *(u32x4*)(dp + i * 16) = u;
        }
    }
    __syncthreads();

    // ---- epilogue: out = [ctxn, Q] @ W + b (bf16; Q reloaded) ----
    bf16x8 qe[2][8];
#pragma unroll
    for (int rt = 0; rt < 2; ++rt)
#pragma unroll
        for (int t8 = 0; t8 < 8; ++t8) {
            const float* rp = qbase + (size_t)rt * 16 * DIM + t8 * 32;
            float4 a = *(const float4*)(rp);
            float4 c = *(const float4*)(rp + 4);
            union { bf16x8 v; unsigned u[4]; } tmp;
            tmp.u[0] = pack2(a.x, a.y); tmp.u[1] = pack2(a.z, a.w);
            tmp.u[2] = pack2(c.x, c.y); tmp.u[3] = pack2(c.z, c.w);
            qe[rt][t8] = tmp.v;
        }
    f32x4 oacc[2][4];
#pragma unroll
    for (int rt = 0; rt < 2; ++rt)
#pragma unroll
        for (int dd = 0; dd < 4; ++dd) oacc[rt][dd] = (f32x4){0.f, 0.f, 0.f, 0.f};
    const uint8_t* wws = ws + WOFF + lane * 16;
    for (int wt = 0; wt < NWT; ++wt) {
        bf16x8 af[2];
#pragma unroll
        for (int rt = 0; rt < 2; ++rt) {
            if (wt < 8) af[rt] = *(const bf16x8*)(cbn + (size_t)(rt * 16 + nn) * 528 + wt * 64 + g * 16);
            else        af[rt] = qe[rt][wt - 8];
        }
#pragma unroll
        for (int dd = 0; dd < 4; ++dd) {
            bf16x8 wf = *(const bf16x8*)(wws + (size_t)(wt * 16 + wid * 4 + dd) * 1024);
#pragma unroll
            for (int rt = 0; rt < 2; ++rt)
                oacc[rt][dd] = __builtin_amdgcn_mfma_f32_16x16x32_bf16(af[rt], wf, oacc[rt][dd], 0, 0, 0);
        }
    }
#pragma unroll
    for (int rt = 0; rt < 2; ++rt) {
        float* obase = out + ((size_t)b * SEQ + q0 + rt * 16) * DIM + wid * 64;
#pragma unroll
        for (int dd = 0; dd < 4; ++dd) {
            float bv = bias[wid * 64 + dd * 16 + nn];
#pragma unroll
            for (int r = 0; r < 4; ++r)
                obase[(size_t)(g * 4 + r) * DIM + dd * 16 + nn] = oacc[rt][dd][r] + bv;
        }
    }
}

extern "C" void kernel_launch(void* const* d_in, const int* in_sizes, int n_in,
                              void* d_out, int out_size, void* d_ws, size_t ws_size,
                              hipStream_t stream) {
    const float* Q    = (const float*)d_in[0];
    const float* K    = (const float*)d_in[1];
    const float* V    = (const float*)d_in[2];
    const float* W    = (const float*)d_in[3];
    const float* bias = (const float*)d_in[4];
    float* out = (float*)d_out;
    uint8_t* ws = (uint8_t*)d_ws;
    prep_frags<<<2 * BATCH * NKV + NWT, 256, 0, stream>>>(K, V, W, ws);
    attn_main<<<BATCH * SEQ / 32, 256, 0, stream>>>(Q, bias, ws, out);
}